// Round 1
// baseline (1032.051 us; speedup 1.0000x reference)
//
#include <hip/hip_runtime.h>

#define B_ 16
#define NF_ 16
#define N_ 1024
#define D_ 128
#define S_ 8
#define NT 1024
#define SCALE_ 0.08838834764831845f

// ---------------- LDS layout ----------------
struct PA {                    // phase A
  float X[128 * 129];          // raw x tile, pitch 129 (scalar access, 2-way free)
  float at[8 * 132];           // dots
  float ap[8 * 132];           // attn * rinv (f4-bcast in P stage)
  float mean[128], rinv[128];
};
struct PB {                    // phase B (overlaps only X/at/ap/mean/rinv via WL/part)
  float WL[128 * 132];         // staged W1/W2/Wqk, XOR-swizzled 16B groups
  float part[4 * 8 * 128];     // k-split partials
  float Pn[8 * 132];           // GRU input vec (P/SS form), f4-aligned
  float gh[8 * 388];
  float gi[8 * 388];
  float hn[8 * 132];
  float buf[8 * 132];          // LN outputs (vec operand)
  float hid[8 * 132];
};
union SMU { PA a; PB b; };
struct Per {                   // persistent across phases
  float h[8 * 132];            // slot state
  float gqW[8 * 132];          // g_in ∘ qW
  float gI[128], bI[128], gF[128], bF[128], gS[128], bS[128];
  float c0s[8], c1s[8], qbs[8], ssp[8], mbp[8], invSS[8];
  float red[48];
};

// ---- fence-free device-coherent accessors (proven pattern from prior kernel) ----
__device__ __forceinline__ float gload(const float* p) {
  return __hip_atomic_load(p, __ATOMIC_RELAXED, __HIP_MEMORY_SCOPE_AGENT);
}
__device__ __forceinline__ void gstore(float* p, float v) {
  __hip_atomic_store(p, v, __ATOMIC_RELAXED, __HIP_MEMORY_SCOPE_AGENT);
}
__device__ __forceinline__ void arrive(unsigned* c) {
  __syncthreads();
  if (threadIdx.x == 0) {
    __builtin_amdgcn_s_waitcnt(0);
    __hip_atomic_fetch_add(c, 1u, __ATOMIC_RELAXED, __HIP_MEMORY_SCOPE_AGENT);
  }
}
__device__ __forceinline__ void wait_for(unsigned* c, unsigned target) {
  if (threadIdx.x == 0) {
    while (__hip_atomic_load(c, __ATOMIC_RELAXED, __HIP_MEMORY_SCOPE_AGENT) < target)
      __builtin_amdgcn_s_sleep(1);
  }
  __syncthreads();
}
__device__ __forceinline__ float sigm(float x) { return 1.f / (1.f + __expf(-x)); }
__device__ __forceinline__ float tanh_f(float x) { return 1.f - 2.f / (1.f + __expf(2.f * x)); }

// stage a 128x128 row-major matrix into LDS, pitch 132, XOR-swizzled 16B groups
__device__ __forceinline__ void stage_w(float* WL, const float* __restrict__ W, int t) {
#pragma unroll
  for (int i = 0; i < 4; ++i) {
    int idx = t + i * 1024;
    int r = idx >> 5, k4 = idx & 31;
    const float4 v = *(const float4*)(W + r * 128 + k4 * 4);
    *(float4*)&WL[r * 132 + ((k4 ^ (r & 7)) << 2)] = v;
  }
}

// k-split: WL(128x128, swizzled) @ 8 vectors (pitch 132) -> part[kc][s][r]
__device__ __forceinline__ void wmat8(SMU& sm, const float* vecs, int t) {
  if (t < 512) {
    int r = t & 127, kc = t >> 7;
    float acc[8] = {0.f,0.f,0.f,0.f,0.f,0.f,0.f,0.f};
#pragma unroll
    for (int g = 0; g < 8; ++g) {
      int k4 = kc * 8 + g;
      const float4 wv = *(const float4*)&sm.b.WL[r * 132 + ((k4 ^ (r & 7)) << 2)];
#pragma unroll
      for (int s2 = 0; s2 < 8; ++s2) {
        const float4 vv = *(const float4*)&vecs[s2 * 132 + k4 * 4];
        acc[s2] += wv.x * vv.x + wv.y * vv.y + wv.z * vv.z + wv.w * vv.w;
      }
    }
#pragma unroll
    for (int s2 = 0; s2 < 8; ++s2) sm.b.part[(kc * 8 + s2) * 128 + r] = acc[s2];
  }
}

// h (Per) -> LN_sl -> qW via Wqk fold -> gqW, c0s, c1s (all 1024 threads)
__device__ void slot_to_qw(SMU& sm, Per& P,
    const float* __restrict__ Wqk, const float* __restrict__ bqk,
    const float* __restrict__ wqbk, const float* __restrict__ bqbk, int t) {
  int s = t >> 7, d = t & 127, w = t >> 6, lane = t & 63;
  float v = P.h[s * 132 + d];
  float a1 = v, a2 = v * v;
#pragma unroll
  for (int off = 32; off; off >>= 1) { a1 += __shfl_down(a1, off); a2 += __shfl_down(a2, off); }
  if (lane == 0) { P.red[w] = a1; P.red[16 + w] = a2; }
  __syncthreads();
  float m = (P.red[2 * s] + P.red[2 * s + 1]) * (1.f / 128.f);
  float var = (P.red[16 + 2 * s] + P.red[16 + 2 * s + 1]) * (1.f / 128.f) - m * m;
  float inv = rsqrtf(var + 1e-5f);
  float nv = (v - m) * inv * P.gS[d] + P.bS[d];
  sm.b.buf[s * 132 + d] = nv;
  float qp = wqbk[d] * nv;
#pragma unroll
  for (int off = 32; off; off >>= 1) qp += __shfl_down(qp, off);
  if (lane == 0) P.red[32 + w] = qp;
  stage_w(sm.b.WL, Wqk, t);
  __syncthreads();
  if (t < 8) P.qbs[t] = P.red[32 + 2 * t] + P.red[32 + 2 * t + 1] + bqbk[0];
  wmat8(sm, sm.b.buf, t);
  __syncthreads();
  {
    int r = d;
    float qv = bqk[r];
#pragma unroll
    for (int kc = 0; kc < 4; ++kc) qv += sm.b.part[(kc * 8 + s) * 128 + r];
    float gq = P.gI[r] * qv;
    P.gqW[s * 132 + r] = gq;
    float p1 = gq, p0 = P.bI[r] * qv;
#pragma unroll
    for (int off = 32; off; off >>= 1) { p1 += __shfl_down(p1, off); p0 += __shfl_down(p0, off); }
    if (lane == 0) { P.red[w] = p1; P.red[16 + w] = p0; }
  }
  __syncthreads();
  if (t < 8) {
    P.c1s[t] = P.red[2 * t] + P.red[2 * t + 1];
    P.c0s[t] = P.red[16 + 2 * t] + P.red[16 + 2 * t + 1] + P.qbs[t];
  }
  __syncthreads();
}

// one-shot algebraic folds: Wiv = Wih@Wv, bihv = Wih@bv+bih, Wqk = Wk^T@Wq,
// bqk = Wk^T@bq, wqbk = Wq^T@bk, bqbk = bq.bk
__global__ __launch_bounds__(128) void precomp(
    const float* __restrict__ Wih, const float* __restrict__ bih,
    const float* __restrict__ Wv, const float* __restrict__ bv,
    const float* __restrict__ Wq, const float* __restrict__ bq,
    const float* __restrict__ Wk, const float* __restrict__ bk,
    float* Wiv, float* bihv, float* Wqk, float* bqk, float* wqbk, float* bqbk) {
  __shared__ float r2[2];
  int r = blockIdx.x, t = threadIdx.x;
  if (r < 384) {
    float acc = 0.f;
#pragma unroll 8
    for (int k = 0; k < 128; ++k) acc += Wih[r * 128 + k] * Wv[k * 128 + t];
    Wiv[r * 128 + t] = acc;
    float p = Wih[r * 128 + t] * bv[t];
#pragma unroll
    for (int off = 32; off; off >>= 1) p += __shfl_down(p, off);
    if ((t & 63) == 0) r2[t >> 6] = p;
    __syncthreads();
    if (t == 0) bihv[r] = r2[0] + r2[1] + bih[r];
  } else {
    int c = r - 384;
    float acc = 0.f;
#pragma unroll 8
    for (int dd = 0; dd < 128; ++dd) acc += Wk[dd * 128 + c] * Wq[dd * 128 + t];
    Wqk[c * 128 + t] = acc;
    float p = Wk[t * 128 + c] * bq[t];
#pragma unroll
    for (int off = 32; off; off >>= 1) p += __shfl_down(p, off);
    if ((t & 63) == 0) r2[t >> 6] = p;
    __syncthreads();
    if (t == 0) bqk[c] = r2[0] + r2[1];
    if (c == 0) {
      float a2 = 0.f;
#pragma unroll 8
      for (int dd = 0; dd < 128; ++dd) a2 += Wq[dd * 128 + t] * bk[dd];
      wqbk[t] = a2;
      float p2 = bq[t] * bk[t];
#pragma unroll
      for (int off = 32; off; off >>= 1) p2 += __shfl_down(p2, off);
      __syncthreads();
      if ((t & 63) == 0) r2[t >> 6] = p2;
      __syncthreads();
      if (t == 0) bqbk[0] = r2[0] + r2[1];
    }
  }
}

__global__ __launch_bounds__(NT) void slot_fused(
    const float* __restrict__ x, const float* __restrict__ slots_init,
    const float* __restrict__ Whh, const float* __restrict__ bhh,
    const float* __restrict__ W1, const float* __restrict__ b1,
    const float* __restrict__ W2, const float* __restrict__ b2,
    const float* __restrict__ g_in, const float* __restrict__ be_in,
    const float* __restrict__ g_sl, const float* __restrict__ be_sl,
    const float* __restrict__ g_ff, const float* __restrict__ be_ff,
    const float* __restrict__ Wiv, const float* __restrict__ bihv,
    const float* __restrict__ Wqk, const float* __restrict__ bqk,
    const float* __restrict__ wqbk, const float* __restrict__ bqbk,
    float* out_slots, float* out_attn,
    unsigned* cnt, float* Ppart, float* Spart) {
  __shared__ __align__(16) SMU sm;
  __shared__ __align__(16) Per P;
  int t = threadIdx.x, bid = blockIdx.x;
  int b = bid >> 3, jb = bid & 7;
  unsigned* cb = cnt + (b << 6);
  int s = t >> 7, d = t & 127, w = t >> 6, lane = t & 63;

  if (t < 128) {
    P.gI[t] = g_in[t]; P.bI[t] = be_in[t];
    P.gF[t] = g_ff[t]; P.bF[t] = be_ff[t];
    P.gS[t] = g_sl[t]; P.bS[t] = be_sl[t];
  }
  P.h[s * 132 + d] = slots_init[s * 128 + d];
  float4 pf[4];
  {
    const float* xs = x + ((long)b * NF_ * N_ + jb * 128) * D_;
#pragma unroll
    for (int i = 0; i < 4; ++i) {
      int ch = t + i * 1024;
      pf[i] = *(const float4*)(xs + (ch >> 5) * 128 + (ch & 31) * 4);
    }
  }
  __syncthreads();
  slot_to_qw(sm, P, Wqk, bqk, wqbk, bqbk, t);

  for (int it = 0; it <= 16; ++it) {
    int f = (it == 0) ? 0 : it - 1;
    int wo = it > 0;
    int par = it & 1;
    // ---------- phase A: stage X ----------
#pragma unroll
    for (int i = 0; i < 4; ++i) {
      int ch = t + i * 1024;
      float* dst = sm.a.X + (ch >> 5) * 129 + (ch & 31) * 4;
      dst[0] = pf[i].x; dst[1] = pf[i].y; dst[2] = pf[i].z; dst[3] = pf[i].w;
    }
    __syncthreads();
    // row stats (LN folded; no normalize pass)
    {
      int r = t >> 3, p8 = t & 7;
      const float* row = sm.a.X + r * 129 + p8 * 16;
      float s1 = 0.f, s2 = 0.f;
#pragma unroll
      for (int i = 0; i < 16; ++i) { float vv = row[i]; s1 += vv; s2 += vv * vv; }
      s1 += __shfl_down(s1, 1); s2 += __shfl_down(s2, 1);
      s1 += __shfl_down(s1, 2); s2 += __shfl_down(s2, 2);
      s1 += __shfl_down(s1, 4); s2 += __shfl_down(s2, 4);
      if (p8 == 0) {
        float m = s1 * (1.f / 128.f);
        sm.a.mean[r] = m;
        sm.a.rinv[r] = rsqrtf(s2 * (1.f / 128.f) - m * m + 1e-5f);
      }
    }
    __syncthreads();
    // dots: at[s][j] = ((x_j . gqW_s) - m_j*c1_s)*rinv_j + c0_s, scaled
    {
      int j = d;
      const float* xr = sm.a.X + j * 129;
      const float* qr = P.gqW + s * 132;
      float acc = 0.f;
#pragma unroll 8
      for (int k4 = 0; k4 < 32; ++k4) {
        const float4 q4 = *(const float4*)&qr[k4 * 4];
        acc += xr[k4 * 4 + 0] * q4.x + xr[k4 * 4 + 1] * q4.y +
               xr[k4 * 4 + 2] * q4.z + xr[k4 * 4 + 3] * q4.w;
      }
      float val = (acc - sm.a.mean[j] * P.c1s[s]) * sm.a.rinv[j] + P.c0s[s];
      sm.a.at[s * 132 + j] = val * SCALE_;
    }
    __syncthreads();
    // softmax over slots (redundant per (s,j)) + attn out + ssm/mbar partials
    {
      int j = d;
      float vv[8]; float mx = -1e30f;
#pragma unroll
      for (int ss = 0; ss < 8; ++ss) { vv[ss] = sm.a.at[ss * 132 + j]; mx = fmaxf(mx, vv[ss]); }
      float sum = 0.f, mine = 0.f;
#pragma unroll
      for (int ss = 0; ss < 8; ++ss) { float e = __expf(vv[ss] - mx); sum += e; if (ss == s) mine = e; }
      float attn = mine / sum + 1e-8f;
      if (wo) out_attn[(((long)b * NF_ + f) * S_ + s) * N_ + jb * 128 + j] = attn;
      float riv = sm.a.rinv[j];
      sm.a.ap[s * 132 + j] = attn * riv;
      float a1 = attn, a2 = attn * sm.a.mean[j] * riv;
#pragma unroll
      for (int off = 32; off; off >>= 1) { a1 += __shfl_down(a1, off); a2 += __shfl_down(a2, off); }
      if (lane == 0) { P.red[w] = a1; P.red[16 + w] = a2; }
    }
    __syncthreads();
    if (t < 8) {
      float* Spub = Spart + (((b * 2 + par) * 8 + jb) * 16);
      gstore(&Spub[t], P.red[2 * t] + P.red[2 * t + 1]);
      gstore(&Spub[8 + t], P.red[16 + 2 * t] + P.red[16 + 2 * t + 1]);
    }
    // P partials: U[s][k] = sum_j ap[s][j] * x[j][k]  (k in lanes>>3, jc split in 8 lanes)
    {
      int k = t >> 3, jc = t & 7;
      float acc[8] = {0.f,0.f,0.f,0.f,0.f,0.f,0.f,0.f};
#pragma unroll
      for (int j4 = 0; j4 < 4; ++j4) {
        int j0 = jc * 16 + j4 * 4;
        float xv0 = sm.a.X[(j0 + 0) * 129 + k];
        float xv1 = sm.a.X[(j0 + 1) * 129 + k];
        float xv2 = sm.a.X[(j0 + 2) * 129 + k];
        float xv3 = sm.a.X[(j0 + 3) * 129 + k];
#pragma unroll
        for (int s2 = 0; s2 < 8; ++s2) {
          const float4 av = *(const float4*)&sm.a.ap[s2 * 132 + j0];
          acc[s2] += av.x * xv0 + av.y * xv1 + av.z * xv2 + av.w * xv3;
        }
      }
#pragma unroll
      for (int off = 1; off < 8; off <<= 1) {
#pragma unroll
        for (int s2 = 0; s2 < 8; ++s2) acc[s2] += __shfl_down(acc[s2], off);
      }
      if (jc == 0) {
        float* Ppub = Ppart + (((b * 2 + par) * 8 + jb) * 1024);
#pragma unroll
        for (int s2 = 0; s2 < 8; ++s2) gstore(&Ppub[s2 * 128 + k], acc[s2]);
      }
    }
    arrive(cb);
    if (it < 16) {  // prefetch next frame while partners finish
      const float* xs = x + (((long)b * NF_ + it) * N_ + jb * 128) * D_;
#pragma unroll
      for (int i = 0; i < 4; ++i) {
        int ch = t + i * 1024;
        pf[i] = *(const float4*)(xs + (ch >> 5) * 128 + (ch & 31) * 4);
      }
    }
    wait_for(cb, 8u * (it + 1));
    // ---------- phase B (redundant in all 8 blocks of this batch) ----------
    float uval = 0.f;
    {
      const float* Pp = Ppart + ((b * 2 + par) * 8) * 1024;
#pragma unroll
      for (int blk = 0; blk < 8; ++blk) uval += gload(&Pp[blk * 1024 + s * 128 + d]);
    }
    if (t < 64) {
      int s2 = t >> 3, blk = t & 7;
      const float* Sp = Spart + ((b * 2 + par) * 8) * 16;
      float sv = gload(&Sp[blk * 16 + s2]);
      float mv = gload(&Sp[blk * 16 + 8 + s2]);
#pragma unroll
      for (int off = 4; off; off >>= 1) { sv += __shfl_down(sv, off); mv += __shfl_down(mv, off); }
      if (blk == 0) { P.ssp[s2] = sv; P.mbp[s2] = mv; P.invSS[s2] = 1.f / sv; }
    }
    __syncthreads();
    sm.b.Pn[s * 132 + d] = P.gI[d] * (uval - P.mbp[s]) * P.invSS[s] + P.bI[d];
    __syncthreads();
    // gh = Whh@h + bhh ; gi = Wiv@Pn + bihv   (slot-batched, 2 rows/thread)
    if (t < 384) {
      int r0 = t * 2;
      bool isH = t < 192;
      const float* Wr = isH ? (Whh + (long)r0 * 128) : (Wiv + (long)(r0 - 384) * 128);
      const float* vec = isH ? P.h : sm.b.Pn;
      float bb0 = isH ? bhh[r0] : bihv[r0 - 384];
      float bb1 = isH ? bhh[r0 + 1] : bihv[r0 - 383];
      float a0[8] = {0.f,0.f,0.f,0.f,0.f,0.f,0.f,0.f};
      float a1v[8] = {0.f,0.f,0.f,0.f,0.f,0.f,0.f,0.f};
#pragma unroll 4
      for (int k4 = 0; k4 < 32; ++k4) {
        const float4 w0 = *(const float4*)(Wr + k4 * 4);
        const float4 w1 = *(const float4*)(Wr + 128 + k4 * 4);
#pragma unroll
        for (int s2 = 0; s2 < 8; ++s2) {
          const float4 vv = *(const float4*)&vec[s2 * 132 + k4 * 4];
          a0[s2] += w0.x * vv.x + w0.y * vv.y + w0.z * vv.z + w0.w * vv.w;
          a1v[s2] += w1.x * vv.x + w1.y * vv.y + w1.z * vv.z + w1.w * vv.w;
        }
      }
      float* og = isH ? sm.b.gh : sm.b.gi;
      int rr = isH ? r0 : r0 - 384;
#pragma unroll
      for (int s2 = 0; s2 < 8; ++s2) {
        og[s2 * 388 + rr] = a0[s2] + bb0;
        og[s2 * 388 + rr + 1] = a1v[s2] + bb1;
      }
    }
    __syncthreads();
    // gates -> hn -> LN_ff
    float hnew;
    {
      const float* gis = sm.b.gi + s * 388;
      const float* ghs = sm.b.gh + s * 388;
      float gr = sigm(gis[d] + ghs[d]);
      float gz = sigm(gis[128 + d] + ghs[128 + d]);
      float gn = tanh_f(gis[256 + d] + gr * ghs[256 + d]);
      hnew = (1.f - gz) * gn + gz * P.h[s * 132 + d];
      sm.b.hn[s * 132 + d] = hnew;
      float a1 = hnew, a2 = hnew * hnew;
#pragma unroll
      for (int off = 32; off; off >>= 1) { a1 += __shfl_down(a1, off); a2 += __shfl_down(a2, off); }
      if (lane == 0) { P.red[w] = a1; P.red[16 + w] = a2; }
    }
    __syncthreads();
    {
      float m = (P.red[2 * s] + P.red[2 * s + 1]) * (1.f / 128.f);
      float var = (P.red[16 + 2 * s] + P.red[16 + 2 * s + 1]) * (1.f / 128.f) - m * m;
      float inv = rsqrtf(var + 1e-5f);
      sm.b.buf[s * 132 + d] = (hnew - m) * inv * P.gF[d] + P.bF[d];
    }
    stage_w(sm.b.WL, W1, t);
    __syncthreads();
    wmat8(sm, sm.b.buf, t);
    __syncthreads();
    {
      float hv = b1[d];
#pragma unroll
      for (int kc = 0; kc < 4; ++kc) hv += sm.b.part[(kc * 8 + s) * 128 + d];
      sm.b.hid[s * 132 + d] = fmaxf(hv, 0.f);
    }
    stage_w(sm.b.WL, W2, t);
    __syncthreads();
    wmat8(sm, sm.b.hid, t);
    __syncthreads();
    {
      float ff = b2[d];
#pragma unroll
      for (int kc = 0; kc < 4; ++kc) ff += sm.b.part[(kc * 8 + s) * 128 + d];
      float sn = sm.b.hn[s * 132 + d] + ff;
      P.h[s * 132 + d] = sn;
      if (wo) out_slots[(((long)b * NF_ + f) * S_ + s) * D_ + d] = sn;
    }
    if (it < 16) slot_to_qw(sm, P, Wqk, bqk, wqbk, bqbk, t);
  }
}

extern "C" void kernel_launch(void* const* d_in, const int* in_sizes, int n_in,
                              void* d_out, int out_size, void* d_ws, size_t ws_size,
                              hipStream_t stream) {
  const float* inputs     = (const float*)d_in[0];
  const float* slots_init = (const float*)d_in[1];
  const float* Wq  = (const float*)d_in[2];
  const float* bq  = (const float*)d_in[3];
  const float* Wk  = (const float*)d_in[4];
  const float* bk  = (const float*)d_in[5];
  const float* Wv  = (const float*)d_in[6];
  const float* bv  = (const float*)d_in[7];
  const float* W1  = (const float*)d_in[8];
  const float* b1  = (const float*)d_in[9];
  const float* W2  = (const float*)d_in[10];
  const float* b2  = (const float*)d_in[11];
  const float* Wih = (const float*)d_in[12];
  const float* Whh = (const float*)d_in[13];
  const float* bih = (const float*)d_in[14];
  const float* bhh = (const float*)d_in[15];
  const float* g_in  = (const float*)d_in[16];
  const float* be_in = (const float*)d_in[17];
  const float* g_sl  = (const float*)d_in[18];
  const float* be_sl = (const float*)d_in[19];
  const float* g_ff  = (const float*)d_in[20];
  const float* be_ff = (const float*)d_in[21];

  float* out_slots = (float*)d_out;
  float* out_attn  = out_slots + (size_t)B_ * NF_ * S_ * D_;

  char* ws = (char*)d_ws;
  unsigned* cnt = (unsigned*)ws;                        // 16 counters, 256 B apart (4 KB)
  float* Wiv   = (float*)(ws + 4096);                   // 384x128  = 196608 B
  float* bihv  = (float*)(ws + 201728 - 1024);          // 200704: 384 floats (1536 B)
  float* Wqk   = (float*)(ws + 202240);                 // 128x128  = 65536 B
  float* bqk   = (float*)(ws + 267776);                 // 512 B
  float* wqbk  = (float*)(ws + 268288);                 // 512 B
  float* bqbk  = (float*)(ws + 268800);                 // 256 B pad
  float* Ppart = (float*)(ws + 269056);                 // 16*2*8*1024*4 = 1 MB
  float* Spart = (float*)(ws + 269056 + 1048576);       // 8 KB

  hipMemsetAsync(d_ws, 0, 4096, stream);  // zero counters (graph-capturable)

  precomp<<<512, 128, 0, stream>>>(Wih, bih, Wv, bv, Wq, bq, Wk, bk,
                                   Wiv, bihv, Wqk, bqk, wqbk, bqbk);
  slot_fused<<<128, NT, 0, stream>>>(inputs, slots_init, Whh, bhh, W1, b1, W2, b2,
      g_in, be_in, g_sl, be_sl, g_ff, be_ff, Wiv, bihv, Wqk, bqk, wqbk, bqbk,
      out_slots, out_attn, cnt, Ppart, Spart);
}